// Round 4
// baseline (226.930 us; speedup 1.0000x reference)
//
#include <hip/hip_runtime.h>
#include <hip/hip_bf16.h>

// GraphConvolution: out = (adj_agg o (X @ W)) + bias  restructured as
//   out = X @ W' + bias,  W'[k,r] = sum_{e: rows[e]==r} vals[e] * W[k, cols[e]]
// (aggregation acts on W's column dim -> commutes with the GEMM).
// N=2048, D_IN=1024, D_OUT=8192, E=131072.

#define N_ROWS 2048
#define D_IN   1024
#define D_OUT  8192

typedef __attribute__((ext_vector_type(8))) short bf16x8;
typedef __attribute__((ext_vector_type(4))) float f32x4;

__device__ __forceinline__ float bf2f(unsigned short u) {
    union { unsigned int i; float f; } x; x.i = ((unsigned int)u) << 16; return x.f;
}
__device__ __forceinline__ unsigned short f2bf(float f) {
    union { unsigned int i; float f; } x; x.f = f;
    unsigned int r = x.i + 0x7FFFu + ((x.i >> 16) & 1u);   // round-nearest-even
    return (unsigned short)(r >> 16);
}

// async global->LDS, 16B per lane; LDS dest = wave-uniform base + lane*16
__device__ __forceinline__ void async_load16(const void* g, void* l) {
    __builtin_amdgcn_global_load_lds(
        (const __attribute__((address_space(1))) void*)g,
        (__attribute__((address_space(3))) void*)l,
        16, 0, 0);
}

// ---------------- stage 1: W [D_IN, D_OUT] f32 -> W^T [D_OUT, D_IN] bf16 ----
__global__ __launch_bounds__(256) void transpose_convert(
    const float* __restrict__ w, unsigned short* __restrict__ wt)
{
    __shared__ float tile[32][33];
    const int bx = blockIdx.x;          // D_OUT/32 = 256
    const int by = blockIdx.y;          // D_IN/32  = 32
    const int tx = threadIdx.x & 31;
    const int ty = threadIdx.x >> 5;    // 0..7
    #pragma unroll
    for (int j = 0; j < 32; j += 8)
        tile[ty + j][tx] = w[(size_t)(by * 32 + ty + j) * D_OUT + bx * 32 + tx];
    __syncthreads();
    #pragma unroll
    for (int j = 0; j < 32; j += 8)
        wt[(size_t)(bx * 32 + ty + j) * D_IN + by * 32 + tx] = f2bf(tile[tx][ty + j]);
}

// ---------------- stage 2: X f32 -> bf16 ------------------------------------
__global__ __launch_bounds__(256) void convert_input(
    const float* __restrict__ in, unsigned short* __restrict__ out)
{
    const int i = (blockIdx.x * 256 + threadIdx.x) * 4;   // sizes divide exactly
    const float4 v = *(const float4*)(in + i);
    ushort4 o; o.x = f2bf(v.x); o.y = f2bf(v.y); o.z = f2bf(v.z); o.w = f2bf(v.w);
    *(ushort4*)(out + i) = o;
}

// ---------------- stage 3: CSR build ----------------------------------------
__global__ void count_rows(const int* __restrict__ rows, int* counts, int E) {
    int e = blockIdx.x * blockDim.x + threadIdx.x;
    if (e < E) atomicAdd(&counts[rows[e]], 1);
}

__global__ __launch_bounds__(1024) void scan_8192(
    const int* __restrict__ counts, int* __restrict__ offsets)
{
    __shared__ int part[1024];
    const int t = threadIdx.x;
    int loc[8];
    int s = 0;
    #pragma unroll
    for (int j = 0; j < 8; ++j) { loc[j] = s; s += counts[t * 8 + j]; }
    part[t] = s;
    __syncthreads();
    for (int off = 1; off < 1024; off <<= 1) {
        int v = (t >= off) ? part[t - off] : 0;
        __syncthreads();
        part[t] += v;
        __syncthreads();
    }
    const int base = (t == 0) ? 0 : part[t - 1];
    #pragma unroll
    for (int j = 0; j < 8; ++j) offsets[t * 8 + j] = base + loc[j];
    if (t == 1023) offsets[8192] = part[1023];
}

// store cols/vals directly in CSR order (kills the eids indirection)
__global__ void fill_csr(const int* __restrict__ rows, const int* __restrict__ cols,
                         const float* __restrict__ vals, const int* __restrict__ offsets,
                         int* cursors, int* __restrict__ csr_cols,
                         float* __restrict__ csr_vals, int E) {
    int e = blockIdx.x * blockDim.x + threadIdx.x;
    if (e < E) {
        int r = rows[e];
        int pos = atomicAdd(&cursors[r], 1);
        int d = offsets[r] + pos;
        csr_cols[d] = cols[e];
        csr_vals[d] = vals[e];
    }
}

// ---------------- stage 4: W'^T[r,:] = sum vals[e] * W^T[cols[e],:] ---------
// One dispatch per k-chunk (kc=0..7), serialized by stream order: the live
// gather working set during a dispatch is exactly one 8192x128 bf16 slice
// = 2 MB -> resident in every XCD's 4 MB L2. Dispatch boundaries give a
// HARD phase separation (R2's spatial %8 and R3's dispatch-order temporal
// tricks both failed to keep chunks from smearing together).
// 4 waves/block, one row per wave, edge loop unrolled x8 for MLP.
__global__ __launch_bounds__(256) void aggregate_rows(
    const unsigned short* __restrict__ wtb,   // W^T [D_OUT, D_IN] bf16
    const int* __restrict__ offsets,
    const int* __restrict__ csr_cols,
    const float* __restrict__ csr_vals,
    unsigned short* __restrict__ wpt,         // W'^T [D_OUT, D_IN] bf16
    int kc)
{
    const int wave = threadIdx.x >> 6;
    const int lane = threadIdx.x & 63;
    const int r    = blockIdx.x * 4 + wave;   // row handled by this wave
    const int k0   = kc * 128 + lane * 2;

    const int beg = offsets[r], end = offsets[r + 1];
    float a0 = 0.f, a1 = 0.f, b0 = 0.f, b1 = 0.f;
    float c0 = 0.f, c1 = 0.f, d0 = 0.f, d1 = 0.f;
    int i = beg;
    for (; i + 8 <= end; i += 8) {            // 8 independent gathers in flight
        int   cc[8]; float vv[8]; ushort2 ww[8];
        #pragma unroll
        for (int j = 0; j < 8; ++j) { cc[j] = csr_cols[i + j]; vv[j] = csr_vals[i + j]; }
        #pragma unroll
        for (int j = 0; j < 8; ++j)
            ww[j] = *(const ushort2*)&wtb[(size_t)cc[j] * D_IN + k0];
        a0 += vv[0] * bf2f(ww[0].x); a1 += vv[0] * bf2f(ww[0].y);
        b0 += vv[1] * bf2f(ww[1].x); b1 += vv[1] * bf2f(ww[1].y);
        c0 += vv[2] * bf2f(ww[2].x); c1 += vv[2] * bf2f(ww[2].y);
        d0 += vv[3] * bf2f(ww[3].x); d1 += vv[3] * bf2f(ww[3].y);
        a0 += vv[4] * bf2f(ww[4].x); a1 += vv[4] * bf2f(ww[4].y);
        b0 += vv[5] * bf2f(ww[5].x); b1 += vv[5] * bf2f(ww[5].y);
        c0 += vv[6] * bf2f(ww[6].x); c1 += vv[6] * bf2f(ww[6].y);
        d0 += vv[7] * bf2f(ww[7].x); d1 += vv[7] * bf2f(ww[7].y);
    }
    for (; i < end; ++i) {
        const int c = csr_cols[i];
        const float v = csr_vals[i];
        const ushort2 w = *(const ushort2*)&wtb[(size_t)c * D_IN + k0];
        a0 += v * bf2f(w.x); a1 += v * bf2f(w.y);
    }
    ushort2 o; o.x = f2bf((a0 + b0) + (c0 + d0)); o.y = f2bf((a1 + b1) + (c1 + d1));
    *(ushort2*)&wpt[(size_t)r * D_IN + k0] = o;
}

// ---------------- stage 5: C = A @ B^T + bias -------------------------------
// A [N_ROWS, D_IN] bf16, B [D_OUT, D_IN] bf16 (= W'^T), C [N_ROWS, D_OUT] f32.
// 128x128 tile, BK=64 (16 iters, 32 MFMA/wave per barrier pair), 4 waves 2x2.
// LDS rows are 128 B (8 chunks of 16 B); chunk c of row r stored at physical
// chunk c ^ (r & 7)  -> fragment reads spread 16 lanes over all 8 chunk-slots
// (2-way aliasing = free, m136); R3 measured SQ_LDS_BANK_CONFLICT = 0.
__global__ __launch_bounds__(256, 4) void gemm_bt_bias(
    const unsigned short* __restrict__ A,
    const unsigned short* __restrict__ B,
    const float*  __restrict__ bias,
    float* __restrict__ C)
{
    __shared__ unsigned short As[128 * 64];   // 16 KB
    __shared__ unsigned short Bs[128 * 64];   // 16 KB

    const int tid  = threadIdx.x;
    const int wave = tid >> 6;
    const int lane = tid & 63;
    const int quad = lane >> 4;
    const int l16  = lane & 15;
    const int wr   = wave >> 1;    // 0..1  (A rows)
    const int wc   = wave & 1;     // 0..1  (B rows = out cols)

    const int bc = blockIdx.x;     // 0..63  col-chunk (r)
    const int br = blockIdx.y;     // 0..15  row-chunk (n)

    const int lrow = lane >> 3;              // 0..7 row-within-octet
    const int lchk = (lane & 7) ^ lrow;      // logical (source) chunk
    const int ldsb = wave * 4096 + lane * 16;   // byte base in LDS region

    const char* Ab = (const char*)A + (size_t)(br * 128) * (D_IN * 2);
    const char* Bb = (const char*)B + (size_t)(bc * 128) * (D_IN * 2);
    char* AsB = (char*)As;
    char* BsB = (char*)Bs;

    f32x4 acc[4][4];
    #pragma unroll
    for (int i = 0; i < 4; ++i)
        #pragma unroll
        for (int j = 0; j < 4; ++j)
            acc[i][j] = (f32x4){0.f, 0.f, 0.f, 0.f};

    // fragment read pointers: row = wr*64 + mi*16 + l16 (row&7 = l16&7),
    // phys chunk for k-step s: (s*4 + quad) ^ (l16 & 7)
    const int x0 = quad ^ (l16 & 7);
    const unsigned short* apb0 = As + (wr * 64 + l16) * 64 + x0 * 8;
    const unsigned short* apb1 = As + (wr * 64 + l16) * 64 + (x0 ^ 4) * 8;
    const unsigned short* bpb0 = Bs + (wc * 64 + l16) * 64 + x0 * 8;
    const unsigned short* bpb1 = Bs + (wc * 64 + l16) * 64 + (x0 ^ 4) * 8;

    for (int it = 0; it < D_IN / 64; ++it) {
        __syncthreads();                       // prior compute done before overwrite
        const int kb = it * 128;               // byte offset along k
        #pragma unroll
        for (int round = 0; round < 4; ++round) {
            const int row = wave * 32 + round * 8 + lrow;
            async_load16(Ab + (size_t)row * (D_IN * 2) + kb + lchk * 16,
                         AsB + ldsb + round * 1024);
            async_load16(Bb + (size_t)row * (D_IN * 2) + kb + lchk * 16,
                         BsB + ldsb + round * 1024);
        }
        __syncthreads();                       // compiler drains vmcnt(0) here

        #pragma unroll
        for (int s = 0; s < 2; ++s) {
            const unsigned short* ap = s ? apb1 : apb0;
            const unsigned short* bp = s ? bpb1 : bpb0;
            bf16x8 af[4], bf[4];
            #pragma unroll
            for (int mi = 0; mi < 4; ++mi)
                af[mi] = *(const bf16x8*)(ap + mi * 16 * 64);
            #pragma unroll
            for (int ni = 0; ni < 4; ++ni)
                bf[ni] = *(const bf16x8*)(bp + ni * 16 * 64);
            #pragma unroll
            for (int mi = 0; mi < 4; ++mi)
                #pragma unroll
                for (int ni = 0; ni < 4; ++ni)
                    acc[mi][ni] = __builtin_amdgcn_mfma_f32_16x16x32_bf16(
                        af[mi], bf[ni], acc[mi][ni], 0, 0, 0);
        }
    }

    // epilogue: C/D layout col=lane&15, row=quad*4+reg  (m89-verified)
    #pragma unroll
    for (int ni = 0; ni < 4; ++ni) {
        const int col = bc * 128 + wc * 64 + ni * 16 + l16;
        const float bv = bias[col];
        #pragma unroll
        for (int mi = 0; mi < 4; ++mi) {
            const int row0 = br * 128 + wr * 64 + mi * 16 + quad * 4;
            #pragma unroll
            for (int r = 0; r < 4; ++r)
                C[(size_t)(row0 + r) * D_OUT + col] = acc[mi][ni][r] + bv;
        }
    }
}

extern "C" void kernel_launch(void* const* d_in, const int* in_sizes, int n_in,
                              void* d_out, int out_size, void* d_ws, size_t ws_size,
                              hipStream_t stream) {
    (void)n_in; (void)out_size; (void)ws_size;
    const float* input    = (const float*)d_in[0];   // [2048,1024]
    const float* weight   = (const float*)d_in[1];   // [1024,8192]
    const float* bias     = (const float*)d_in[2];   // [8192]
    const int*   adj_rows = (const int*)d_in[3];     // [E]
    const int*   adj_cols = (const int*)d_in[4];     // [E]
    const float* adj_vals = (const float*)d_in[5];   // [E]
    const int E = in_sizes[3];

    // workspace layout (~37.6 MB; ws re-poisoned each call, everything below
    // is fully rewritten or explicitly zeroed every launch)
    char* ws = (char*)d_ws;
    unsigned short* wtb = (unsigned short*)ws;                                // 16 MB  W^T bf16
    unsigned short* wpt = (unsigned short*)(ws + (size_t)16 * 1024 * 1024);   // 16 MB  W'^T bf16
    unsigned short* abf = (unsigned short*)(ws + (size_t)32 * 1024 * 1024);   //  4 MB  X bf16
    int*   counts   = (int*)(ws + (size_t)36 * 1024 * 1024);                  // 32 KB
    int*   cursors  = counts + D_OUT;                                         // 32 KB
    int*   offsets  = cursors + D_OUT;                                        // 32 KB + 4
    int*   csr_cols = offsets + (D_OUT + 1);                                  // 512 KB
    float* csr_vals = (float*)(csr_cols + 131072);                            // 512 KB

    hipMemsetAsync(counts, 0, 2 * D_OUT * sizeof(int), stream);  // counts + cursors
    transpose_convert<<<dim3(D_OUT / 32, D_IN / 32), 256, 0, stream>>>(weight, wtb);
    convert_input<<<(N_ROWS * D_IN) / 1024, 256, 0, stream>>>(input, abf);
    count_rows<<<(E + 255) / 256, 256, 0, stream>>>(adj_rows, counts, E);
    scan_8192<<<1, 1024, 0, stream>>>(counts, offsets);
    fill_csr<<<(E + 255) / 256, 256, 0, stream>>>(adj_rows, adj_cols, adj_vals,
                                                  offsets, cursors, csr_cols, csr_vals, E);
    for (int kc = 0; kc < 8; ++kc)
        aggregate_rows<<<dim3(D_OUT / 4), 256, 0, stream>>>(
            wtb, offsets, csr_cols, csr_vals, wpt, kc);
    gemm_bt_bias<<<dim3(D_OUT / 128, N_ROWS / 128), 256, 0, stream>>>(
        abf, wpt, bias, (float*)d_out);
}

// Round 5
// 195.327 us; speedup vs baseline: 1.1618x; 1.1618x over previous
//
#include <hip/hip_runtime.h>
#include <hip/hip_bf16.h>

// GraphConvolution: out = (adj_agg o (X @ W)) + bias  restructured as
//   out = X @ W' + bias,  W'[k,r] = sum_{e: rows[e]==r} vals[e] * W[k, cols[e]]
// (aggregation acts on W's column dim -> commutes with the GEMM).
// N=2048, D_IN=1024, D_OUT=8192, E=131072.

#define N_ROWS 2048
#define D_IN   1024
#define D_OUT  8192

typedef __attribute__((ext_vector_type(8))) short bf16x8;
typedef __attribute__((ext_vector_type(4))) float f32x4;

__device__ __forceinline__ float bf2f(unsigned short u) {
    union { unsigned int i; float f; } x; x.i = ((unsigned int)u) << 16; return x.f;
}
__device__ __forceinline__ unsigned short f2bf(float f) {
    union { unsigned int i; float f; } x; x.f = f;
    unsigned int r = x.i + 0x7FFFu + ((x.i >> 16) & 1u);   // round-nearest-even
    return (unsigned short)(r >> 16);
}

// async global->LDS, 16B per lane; LDS dest = wave-uniform base + lane*16
__device__ __forceinline__ void async_load16(const void* g, void* l) {
    __builtin_amdgcn_global_load_lds(
        (const __attribute__((address_space(1))) void*)g,
        (__attribute__((address_space(3))) void*)l,
        16, 0, 0);
}

// ---------------- stage 1: W [D_IN, D_OUT] f32 -> W^T [D_OUT, D_IN] bf16 ----
__global__ __launch_bounds__(256) void transpose_convert(
    const float* __restrict__ w, unsigned short* __restrict__ wt)
{
    __shared__ float tile[32][33];
    const int bx = blockIdx.x;          // D_OUT/32 = 256
    const int by = blockIdx.y;          // D_IN/32  = 32
    const int tx = threadIdx.x & 31;
    const int ty = threadIdx.x >> 5;    // 0..7
    #pragma unroll
    for (int j = 0; j < 32; j += 8)
        tile[ty + j][tx] = w[(size_t)(by * 32 + ty + j) * D_OUT + bx * 32 + tx];
    __syncthreads();
    #pragma unroll
    for (int j = 0; j < 32; j += 8)
        wt[(size_t)(bx * 32 + ty + j) * D_IN + by * 32 + tx] = f2bf(tile[tx][ty + j]);
}

// ---------------- stage 2: X f32 -> bf16 ------------------------------------
__global__ __launch_bounds__(256) void convert_input(
    const float* __restrict__ in, unsigned short* __restrict__ out)
{
    const int i = (blockIdx.x * 256 + threadIdx.x) * 4;   // sizes divide exactly
    const float4 v = *(const float4*)(in + i);
    ushort4 o; o.x = f2bf(v.x); o.y = f2bf(v.y); o.z = f2bf(v.z); o.w = f2bf(v.w);
    *(ushort4*)(out + i) = o;
}

// ---------------- stage 3: CSR build ----------------------------------------
__global__ void count_rows(const int* __restrict__ rows, int* counts, int E) {
    int e = blockIdx.x * blockDim.x + threadIdx.x;
    if (e < E) atomicAdd(&counts[rows[e]], 1);
}

__global__ __launch_bounds__(1024) void scan_8192(
    const int* __restrict__ counts, int* __restrict__ offsets)
{
    __shared__ int part[1024];
    const int t = threadIdx.x;
    int loc[8];
    int s = 0;
    #pragma unroll
    for (int j = 0; j < 8; ++j) { loc[j] = s; s += counts[t * 8 + j]; }
    part[t] = s;
    __syncthreads();
    for (int off = 1; off < 1024; off <<= 1) {
        int v = (t >= off) ? part[t - off] : 0;
        __syncthreads();
        part[t] += v;
        __syncthreads();
    }
    const int base = (t == 0) ? 0 : part[t - 1];
    #pragma unroll
    for (int j = 0; j < 8; ++j) offsets[t * 8 + j] = base + loc[j];
    if (t == 1023) offsets[8192] = part[1023];
}

// store cols/vals directly in CSR order (kills the eids indirection)
__global__ void fill_csr(const int* __restrict__ rows, const int* __restrict__ cols,
                         const float* __restrict__ vals, const int* __restrict__ offsets,
                         int* cursors, int* __restrict__ csr_cols,
                         float* __restrict__ csr_vals, int E) {
    int e = blockIdx.x * blockDim.x + threadIdx.x;
    if (e < E) {
        int r = rows[e];
        int pos = atomicAdd(&cursors[r], 1);
        int d = offsets[r] + pos;
        csr_cols[d] = cols[e];
        csr_vals[d] = vals[e];
    }
}

// ---------------- stage 4: W'^T[r,:] = sum vals[e] * W^T[cols[e],:] ---------
// Issue-rate-optimized gather (R2/R3/R4 L2-placement tricks were all neutral:
// the stage is latency/issue bound, not cache-capacity bound).
// One wave per output row r. Per edge the wave consumes the ENTIRE 2 KB
// W^T row as two 1024 B wave-loads (16 B/lane dwordx4, 8x128B lines each):
// 262K total load instrs (4x fewer than R3), unroll x4 edges = 8 gathers
// (16 KB) in flight per wave. 16 fp32 accumulators/lane cover all k.
__global__ __launch_bounds__(256) void aggregate_rows(
    const unsigned short* __restrict__ wtb,   // W^T [D_OUT, D_IN] bf16
    const int* __restrict__ offsets,
    const int* __restrict__ csr_cols,
    const float* __restrict__ csr_vals,
    unsigned short* __restrict__ wpt)         // W'^T [D_OUT, D_IN] bf16
{
    const int wave = threadIdx.x >> 6;
    const int lane = threadIdx.x & 63;
    const int r    = blockIdx.x * 4 + wave;   // row handled by this wave

    const int beg = offsets[r], end = offsets[r + 1];
    float acc[16];
    #pragma unroll
    for (int j = 0; j < 16; ++j) acc[j] = 0.f;

    const int klo = lane * 8;          // seg0: k = klo..klo+7
    // seg1: k = 512 + klo .. 512 + klo + 7

    int i = beg;
    for (; i + 4 <= end; i += 4) {
        int cc[4]; float vv[4]; bf16x8 g0[4], g1[4];
        #pragma unroll
        for (int j = 0; j < 4; ++j) { cc[j] = csr_cols[i + j]; vv[j] = csr_vals[i + j]; }
        #pragma unroll
        for (int j = 0; j < 4; ++j) {
            const unsigned short* rp = wtb + (size_t)cc[j] * D_IN + klo;
            g0[j] = *(const bf16x8*)rp;
            g1[j] = *(const bf16x8*)(rp + 512);
        }
        #pragma unroll
        for (int j = 0; j < 4; ++j) {
            union { bf16x8 s; unsigned int d[4]; } u0, u1;
            u0.s = g0[j]; u1.s = g1[j];
            const float v = vv[j];
            #pragma unroll
            for (int q = 0; q < 4; ++q) {
                union { unsigned int i; float f; } lo, hi;
                lo.i = u0.d[q] << 16;          hi.i = u0.d[q] & 0xffff0000u;
                acc[2 * q]     += v * lo.f;    acc[2 * q + 1] += v * hi.f;
                lo.i = u1.d[q] << 16;          hi.i = u1.d[q] & 0xffff0000u;
                acc[8 + 2 * q] += v * lo.f;    acc[8 + 2 * q + 1] += v * hi.f;
            }
        }
    }
    for (; i < end; ++i) {
        const int c = csr_cols[i];
        const float v = csr_vals[i];
        const unsigned short* rp = wtb + (size_t)c * D_IN + klo;
        const bf16x8 g0 = *(const bf16x8*)rp;
        const bf16x8 g1 = *(const bf16x8*)(rp + 512);
        union { bf16x8 s; unsigned int d[4]; } u0, u1;
        u0.s = g0; u1.s = g1;
        #pragma unroll
        for (int q = 0; q < 4; ++q) {
            union { unsigned int i; float f; } lo, hi;
            lo.i = u0.d[q] << 16;          hi.i = u0.d[q] & 0xffff0000u;
            acc[2 * q]     += v * lo.f;    acc[2 * q + 1] += v * hi.f;
            lo.i = u1.d[q] << 16;          hi.i = u1.d[q] & 0xffff0000u;
            acc[8 + 2 * q] += v * lo.f;    acc[8 + 2 * q + 1] += v * hi.f;
        }
    }

    // pack & store: two 16 B stores per lane
    union { bf16x8 s; unsigned short h[8]; } o0, o1;
    #pragma unroll
    for (int j = 0; j < 8; ++j) { o0.h[j] = f2bf(acc[j]); o1.h[j] = f2bf(acc[8 + j]); }
    unsigned short* wp = wpt + (size_t)r * D_IN + klo;
    *(bf16x8*)wp         = o0.s;
    *(bf16x8*)(wp + 512) = o1.s;
}

// ---------------- stage 5: C = A @ B^T + bias -------------------------------
// A [N_ROWS, D_IN] bf16, B [D_OUT, D_IN] bf16 (= W'^T), C [N_ROWS, D_OUT] f32.
// 128x128 tile, BK=64 (16 iters, 32 MFMA/wave per barrier pair), 4 waves 2x2.
// LDS rows are 128 B (8 chunks of 16 B); chunk c of row r stored at physical
// chunk c ^ (r & 7)  -> fragment reads spread 16 lanes over all 8 chunk-slots
// (2-way aliasing = free, m136); R3 measured SQ_LDS_BANK_CONFLICT = 0.
__global__ __launch_bounds__(256, 4) void gemm_bt_bias(
    const unsigned short* __restrict__ A,
    const unsigned short* __restrict__ B,
    const float*  __restrict__ bias,
    float* __restrict__ C)
{
    __shared__ unsigned short As[128 * 64];   // 16 KB
    __shared__ unsigned short Bs[128 * 64];   // 16 KB

    const int tid  = threadIdx.x;
    const int wave = tid >> 6;
    const int lane = tid & 63;
    const int quad = lane >> 4;
    const int l16  = lane & 15;
    const int wr   = wave >> 1;    // 0..1  (A rows)
    const int wc   = wave & 1;     // 0..1  (B rows = out cols)

    const int bc = blockIdx.x;     // 0..63  col-chunk (r)
    const int br = blockIdx.y;     // 0..15  row-chunk (n)

    const int lrow = lane >> 3;              // 0..7 row-within-octet
    const int lchk = (lane & 7) ^ lrow;      // logical (source) chunk
    const int ldsb = wave * 4096 + lane * 16;   // byte base in LDS region

    const char* Ab = (const char*)A + (size_t)(br * 128) * (D_IN * 2);
    const char* Bb = (const char*)B + (size_t)(bc * 128) * (D_IN * 2);
    char* AsB = (char*)As;
    char* BsB = (char*)Bs;

    f32x4 acc[4][4];
    #pragma unroll
    for (int i = 0; i < 4; ++i)
        #pragma unroll
        for (int j = 0; j < 4; ++j)
            acc[i][j] = (f32x4){0.f, 0.f, 0.f, 0.f};

    // fragment read pointers: row = wr*64 + mi*16 + l16 (row&7 = l16&7),
    // phys chunk for k-step s: (s*4 + quad) ^ (l16 & 7)
    const int x0 = quad ^ (l16 & 7);
    const unsigned short* apb0 = As + (wr * 64 + l16) * 64 + x0 * 8;
    const unsigned short* apb1 = As + (wr * 64 + l16) * 64 + (x0 ^ 4) * 8;
    const unsigned short* bpb0 = Bs + (wc * 64 + l16) * 64 + x0 * 8;
    const unsigned short* bpb1 = Bs + (wc * 64 + l16) * 64 + (x0 ^ 4) * 8;

    for (int it = 0; it < D_IN / 64; ++it) {
        __syncthreads();                       // prior compute done before overwrite
        const int kb = it * 128;               // byte offset along k
        #pragma unroll
        for (int round = 0; round < 4; ++round) {
            const int row = wave * 32 + round * 8 + lrow;
            async_load16(Ab + (size_t)row * (D_IN * 2) + kb + lchk * 16,
                         AsB + ldsb + round * 1024);
            async_load16(Bb + (size_t)row * (D_IN * 2) + kb + lchk * 16,
                         BsB + ldsb + round * 1024);
        }
        __syncthreads();                       // compiler drains vmcnt(0) here

        #pragma unroll
        for (int s = 0; s < 2; ++s) {
            const unsigned short* ap = s ? apb1 : apb0;
            const unsigned short* bp = s ? bpb1 : bpb0;
            bf16x8 af[4], bf[4];
            #pragma unroll
            for (int mi = 0; mi < 4; ++mi)
                af[mi] = *(const bf16x8*)(ap + mi * 16 * 64);
            #pragma unroll
            for (int ni = 0; ni < 4; ++ni)
                bf[ni] = *(const bf16x8*)(bp + ni * 16 * 64);
            #pragma unroll
            for (int mi = 0; mi < 4; ++mi)
                #pragma unroll
                for (int ni = 0; ni < 4; ++ni)
                    acc[mi][ni] = __builtin_amdgcn_mfma_f32_16x16x32_bf16(
                        af[mi], bf[ni], acc[mi][ni], 0, 0, 0);
        }
    }

    // epilogue: C/D layout col=lane&15, row=quad*4+reg  (m89-verified)
    #pragma unroll
    for (int ni = 0; ni < 4; ++ni) {
        const int col = bc * 128 + wc * 64 + ni * 16 + l16;
        const float bv = bias[col];
        #pragma unroll
        for (int mi = 0; mi < 4; ++mi) {
            const int row0 = br * 128 + wr * 64 + mi * 16 + quad * 4;
            #pragma unroll
            for (int r = 0; r < 4; ++r)
                C[(size_t)(row0 + r) * D_OUT + col] = acc[mi][ni][r] + bv;
        }
    }
}

extern "C" void kernel_launch(void* const* d_in, const int* in_sizes, int n_in,
                              void* d_out, int out_size, void* d_ws, size_t ws_size,
                              hipStream_t stream) {
    (void)n_in; (void)out_size; (void)ws_size;
    const float* input    = (const float*)d_in[0];   // [2048,1024]
    const float* weight   = (const float*)d_in[1];   // [1024,8192]
    const float* bias     = (const float*)d_in[2];   // [8192]
    const int*   adj_rows = (const int*)d_in[3];     // [E]
    const int*   adj_cols = (const int*)d_in[4];     // [E]
    const float* adj_vals = (const float*)d_in[5];   // [E]
    const int E = in_sizes[3];

    // workspace layout (~37.6 MB; ws re-poisoned each call, everything below
    // is fully rewritten or explicitly zeroed every launch)
    char* ws = (char*)d_ws;
    unsigned short* wtb = (unsigned short*)ws;                                // 16 MB  W^T bf16
    unsigned short* wpt = (unsigned short*)(ws + (size_t)16 * 1024 * 1024);   // 16 MB  W'^T bf16
    unsigned short* abf = (unsigned short*)(ws + (size_t)32 * 1024 * 1024);   //  4 MB  X bf16
    int*   counts   = (int*)(ws + (size_t)36 * 1024 * 1024);                  // 32 KB
    int*   cursors  = counts + D_OUT;                                         // 32 KB
    int*   offsets  = cursors + D_OUT;                                        // 32 KB + 4
    int*   csr_cols = offsets + (D_OUT + 1);                                  // 512 KB
    float* csr_vals = (float*)(csr_cols + 131072);                            // 512 KB

    hipMemsetAsync(counts, 0, 2 * D_OUT * sizeof(int), stream);  // counts + cursors
    transpose_convert<<<dim3(D_OUT / 32, D_IN / 32), 256, 0, stream>>>(weight, wtb);
    convert_input<<<(N_ROWS * D_IN) / 1024, 256, 0, stream>>>(input, abf);
    count_rows<<<(E + 255) / 256, 256, 0, stream>>>(adj_rows, counts, E);
    scan_8192<<<1, 1024, 0, stream>>>(counts, offsets);
    fill_csr<<<(E + 255) / 256, 256, 0, stream>>>(adj_rows, adj_cols, adj_vals,
                                                  offsets, cursors, csr_cols, csr_vals, E);
    aggregate_rows<<<dim3(D_OUT / 4), 256, 0, stream>>>(
        wtb, offsets, csr_cols, csr_vals, wpt);
    gemm_bt_bias<<<dim3(D_OUT / 128, N_ROWS / 128), 256, 0, stream>>>(
        abf, wpt, bias, (float*)d_out);
}

// Round 6
// 191.501 us; speedup vs baseline: 1.1850x; 1.0200x over previous
//
#include <hip/hip_runtime.h>
#include <hip/hip_bf16.h>

// GraphConvolution: out = (adj_agg o (X @ W)) + bias  restructured as
//   out = X @ W' + bias,  W'[k,r] = sum_{e: rows[e]==r} vals[e] * W[k, cols[e]]
// (aggregation acts on W's column dim -> commutes with the GEMM).
// N=2048, D_IN=1024, D_OUT=8192, E=131072.

#define N_ROWS 2048
#define D_IN   1024
#define D_OUT  8192

typedef __attribute__((ext_vector_type(8))) short bf16x8;
typedef __attribute__((ext_vector_type(4))) float f32x4;
typedef __attribute__((ext_vector_type(2))) float f32x2;

__device__ __forceinline__ float bf2f(unsigned short u) {
    union { unsigned int i; float f; } x; x.i = ((unsigned int)u) << 16; return x.f;
}
__device__ __forceinline__ unsigned short f2bf(float f) {
    union { unsigned int i; float f; } x; x.f = f;
    unsigned int r = x.i + 0x7FFFu + ((x.i >> 16) & 1u);   // round-nearest-even
    return (unsigned short)(r >> 16);
}

// async global->LDS, 16B per lane; LDS dest = wave-uniform base + lane*16
__device__ __forceinline__ void async_load16(const void* g, void* l) {
    __builtin_amdgcn_global_load_lds(
        (const __attribute__((address_space(1))) void*)g,
        (__attribute__((address_space(3))) void*)l,
        16, 0, 0);
}

// ---------------- stage 1: W [D_IN, D_OUT] f32 -> W^T [D_OUT, D_IN] bf16 ----
// 64x64 tiles: reads are float4-coalesced (256 B/row), writes are 64 bf16
// rows of 128 B = full HBM lines (R1-R5's 32x32 version wrote 64 B half-lines).
__global__ __launch_bounds__(256) void transpose_convert(
    const float* __restrict__ w, unsigned short* __restrict__ wt)
{
    __shared__ float tile[64][65];
    const int bx = blockIdx.x;          // D_OUT/64 = 128
    const int by = blockIdx.y;          // D_IN/64  = 16
    const int t  = threadIdx.x;
    #pragma unroll
    for (int pass = 0; pass < 4; ++pass) {
        const int item = pass * 256 + t;
        const int r  = item >> 4;        // 0..63
        const int c4 = item & 15;        // 0..15
        const float4 v = *(const float4*)&w[(size_t)(by * 64 + r) * D_OUT + bx * 64 + c4 * 4];
        tile[r][c4 * 4 + 0] = v.x; tile[r][c4 * 4 + 1] = v.y;
        tile[r][c4 * 4 + 2] = v.z; tile[r][c4 * 4 + 3] = v.w;
    }
    __syncthreads();
    #pragma unroll
    for (int pass = 0; pass < 4; ++pass) {
        const int item = pass * 256 + t;
        const int rr  = item >> 4;       // 0..63 out-row within tile
        const int cc4 = item & 15;       // 0..15
        ushort4 o;
        o.x = f2bf(tile[cc4 * 4 + 0][rr]);
        o.y = f2bf(tile[cc4 * 4 + 1][rr]);
        o.z = f2bf(tile[cc4 * 4 + 2][rr]);
        o.w = f2bf(tile[cc4 * 4 + 3][rr]);
        *(ushort4*)&wt[(size_t)(bx * 64 + rr) * D_IN + by * 64 + cc4 * 4] = o;
    }
}

// ---------------- stage 2: X f32 -> bf16 ------------------------------------
__global__ __launch_bounds__(256) void convert_input(
    const float* __restrict__ in, unsigned short* __restrict__ out)
{
    const int i = (blockIdx.x * 256 + threadIdx.x) * 4;   // sizes divide exactly
    const float4 v = *(const float4*)(in + i);
    ushort4 o; o.x = f2bf(v.x); o.y = f2bf(v.y); o.z = f2bf(v.z); o.w = f2bf(v.w);
    *(ushort4*)(out + i) = o;
}

// ---------------- stage 3: CSR build ----------------------------------------
__global__ void count_rows(const int* __restrict__ rows, int* counts, int E) {
    int e = blockIdx.x * blockDim.x + threadIdx.x;
    if (e < E) atomicAdd(&counts[rows[e]], 1);
}

__global__ __launch_bounds__(1024) void scan_8192(
    const int* __restrict__ counts, int* __restrict__ offsets)
{
    __shared__ int part[1024];
    const int t = threadIdx.x;
    int loc[8];
    int s = 0;
    #pragma unroll
    for (int j = 0; j < 8; ++j) { loc[j] = s; s += counts[t * 8 + j]; }
    part[t] = s;
    __syncthreads();
    for (int off = 1; off < 1024; off <<= 1) {
        int v = (t >= off) ? part[t - off] : 0;
        __syncthreads();
        part[t] += v;
        __syncthreads();
    }
    const int base = (t == 0) ? 0 : part[t - 1];
    #pragma unroll
    for (int j = 0; j < 8; ++j) offsets[t * 8 + j] = base + loc[j];
    if (t == 1023) offsets[8192] = part[1023];
}

// store (col, val) packed as int2 in CSR order -> one 8 B load per edge later
__global__ void fill_csr(const int* __restrict__ rows, const int* __restrict__ cols,
                         const float* __restrict__ vals, const int* __restrict__ offsets,
                         int* cursors, int2* __restrict__ csr_cv, int E) {
    int e = blockIdx.x * blockDim.x + threadIdx.x;
    if (e < E) {
        int r = rows[e];
        int pos = atomicAdd(&cursors[r], 1);
        int2 cv; cv.x = cols[e]; cv.y = __float_as_int(vals[e]);
        csr_cv[offsets[r] + pos] = cv;
    }
}

// ---------------- stage 4: W'^T[r,:] = sum vals[e] * W^T[cols[e],:] ---------
// One wave = one (row, k-half): 512 k's, 8 B/lane, so per edge exactly ONE
// dwordx4 wave-load (1 KB, 8 full lines) + 4 v_pk_fma_f32. Register budget
// ~45 VGPR, __launch_bounds__(256,8) pins 8 waves/SIMD (R5's 16-acc + 32
// gather regs likely crossed the 64-VGPR occupancy cliff, m69). Unroll x4
// edges = 4 KB in flight/wave x 32 waves/CU.
__global__ __launch_bounds__(256, 8) void aggregate_rows(
    const unsigned short* __restrict__ wtb,   // W^T [D_OUT, D_IN] bf16
    const int* __restrict__ offsets,
    const int2* __restrict__ csr_cv,
    unsigned short* __restrict__ wpt)         // W'^T [D_OUT, D_IN] bf16
{
    const int wave = threadIdx.x >> 6;
    const int lane = threadIdx.x & 63;
    const int r    = blockIdx.x * 2 + (wave >> 1);   // 2 rows/block
    const int k0   = (wave & 1) * 512 + lane * 8;    // k-half + lane offset

    const int beg = offsets[r], end = offsets[r + 1];
    f32x2 acc[4];
    #pragma unroll
    for (int q = 0; q < 4; ++q) acc[q] = (f32x2){0.f, 0.f};

    const unsigned short* wb = wtb + k0;
    int i = beg;
    for (; i + 4 <= end; i += 4) {
        int2 cv[4]; bf16x8 g[4];
        #pragma unroll
        for (int j = 0; j < 4; ++j) cv[j] = csr_cv[i + j];
        #pragma unroll
        for (int j = 0; j < 4; ++j)
            g[j] = *(const bf16x8*)(wb + (size_t)cv[j].x * D_IN);
        #pragma unroll
        for (int j = 0; j < 4; ++j) {
            const float v = __int_as_float(cv[j].y);
            const f32x2 vv = (f32x2){v, v};
            union { bf16x8 s; unsigned int d[4]; } u; u.s = g[j];
            #pragma unroll
            for (int q = 0; q < 4; ++q) {
                union { unsigned int i; float f; } lo, hi;
                lo.i = u.d[q] << 16; hi.i = u.d[q] & 0xffff0000u;
                acc[q] += vv * (f32x2){lo.f, hi.f};
            }
        }
    }
    for (; i < end; ++i) {
        const int2 cv = csr_cv[i];
        const float v = __int_as_float(cv.y);
        const f32x2 vv = (f32x2){v, v};
        union { bf16x8 s; unsigned int d[4]; } u;
        u.s = *(const bf16x8*)(wb + (size_t)cv.x * D_IN);
        #pragma unroll
        for (int q = 0; q < 4; ++q) {
            union { unsigned int i; float f; } lo, hi;
            lo.i = u.d[q] << 16; hi.i = u.d[q] & 0xffff0000u;
            acc[q] += vv * (f32x2){lo.f, hi.f};
        }
    }

    union { bf16x8 s; unsigned short h[8]; } o;
    #pragma unroll
    for (int q = 0; q < 4; ++q) {
        o.h[2 * q]     = f2bf(acc[q][0]);
        o.h[2 * q + 1] = f2bf(acc[q][1]);
    }
    *(bf16x8*)(wpt + (size_t)r * D_IN + k0) = o.s;
}

// ---------------- stage 5: C = A @ B^T + bias -------------------------------
// A [N_ROWS, D_IN] bf16, B [D_OUT, D_IN] bf16 (= W'^T), C [N_ROWS, D_OUT] f32.
// 128x128 tile, BK=64 (16 iters, 32 MFMA/wave per barrier pair), 4 waves 2x2.
// LDS rows are 128 B (8 chunks of 16 B); chunk c of row r stored at physical
// chunk c ^ (r & 7)  -> fragment reads spread 16 lanes over all 8 chunk-slots
// (2-way aliasing = free, m136); R3 measured SQ_LDS_BANK_CONFLICT = 0.
// At the m97-structure plateau (~806 TF here) — left unchanged as control.
__global__ __launch_bounds__(256, 4) void gemm_bt_bias(
    const unsigned short* __restrict__ A,
    const unsigned short* __restrict__ B,
    const float*  __restrict__ bias,
    float* __restrict__ C)
{
    __shared__ unsigned short As[128 * 64];   // 16 KB
    __shared__ unsigned short Bs[128 * 64];   // 16 KB

    const int tid  = threadIdx.x;
    const int wave = tid >> 6;
    const int lane = tid & 63;
    const int quad = lane >> 4;
    const int l16  = lane & 15;
    const int wr   = wave >> 1;    // 0..1  (A rows)
    const int wc   = wave & 1;     // 0..1  (B rows = out cols)

    const int bc = blockIdx.x;     // 0..63  col-chunk (r)
    const int br = blockIdx.y;     // 0..15  row-chunk (n)

    const int lrow = lane >> 3;              // 0..7 row-within-octet
    const int lchk = (lane & 7) ^ lrow;      // logical (source) chunk
    const int ldsb = wave * 4096 + lane * 16;   // byte base in LDS region

    const char* Ab = (const char*)A + (size_t)(br * 128) * (D_IN * 2);
    const char* Bb = (const char*)B + (size_t)(bc * 128) * (D_IN * 2);
    char* AsB = (char*)As;
    char* BsB = (char*)Bs;

    f32x4 acc[4][4];
    #pragma unroll
    for (int i = 0; i < 4; ++i)
        #pragma unroll
        for (int j = 0; j < 4; ++j)
            acc[i][j] = (f32x4){0.f, 0.f, 0.f, 0.f};

    // fragment read pointers: row = wr*64 + mi*16 + l16 (row&7 = l16&7),
    // phys chunk for k-step s: (s*4 + quad) ^ (l16 & 7)
    const int x0 = quad ^ (l16 & 7);
    const unsigned short* apb0 = As + (wr * 64 + l16) * 64 + x0 * 8;
    const unsigned short* apb1 = As + (wr * 64 + l16) * 64 + (x0 ^ 4) * 8;
    const unsigned short* bpb0 = Bs + (wc * 64 + l16) * 64 + x0 * 8;
    const unsigned short* bpb1 = Bs + (wc * 64 + l16) * 64 + (x0 ^ 4) * 8;

    for (int it = 0; it < D_IN / 64; ++it) {
        __syncthreads();                       // prior compute done before overwrite
        const int kb = it * 128;               // byte offset along k
        #pragma unroll
        for (int round = 0; round < 4; ++round) {
            const int row = wave * 32 + round * 8 + lrow;
            async_load16(Ab + (size_t)row * (D_IN * 2) + kb + lchk * 16,
                         AsB + ldsb + round * 1024);
            async_load16(Bb + (size_t)row * (D_IN * 2) + kb + lchk * 16,
                         BsB + ldsb + round * 1024);
        }
        __syncthreads();                       // compiler drains vmcnt(0) here

        #pragma unroll
        for (int s = 0; s < 2; ++s) {
            const unsigned short* ap = s ? apb1 : apb0;
            const unsigned short* bp = s ? bpb1 : bpb0;
            bf16x8 af[4], bf[4];
            #pragma unroll
            for (int mi = 0; mi < 4; ++mi)
                af[mi] = *(const bf16x8*)(ap + mi * 16 * 64);
            #pragma unroll
            for (int ni = 0; ni < 4; ++ni)
                bf[ni] = *(const bf16x8*)(bp + ni * 16 * 64);
            #pragma unroll
            for (int mi = 0; mi < 4; ++mi)
                #pragma unroll
                for (int ni = 0; ni < 4; ++ni)
                    acc[mi][ni] = __builtin_amdgcn_mfma_f32_16x16x32_bf16(
                        af[mi], bf[ni], acc[mi][ni], 0, 0, 0);
        }
    }

    // epilogue: C/D layout col=lane&15, row=quad*4+reg  (m89-verified)
    #pragma unroll
    for (int ni = 0; ni < 4; ++ni) {
        const int col = bc * 128 + wc * 64 + ni * 16 + l16;
        const float bv = bias[col];
        #pragma unroll
        for (int mi = 0; mi < 4; ++mi) {
            const int row0 = br * 128 + wr * 64 + mi * 16 + quad * 4;
            #pragma unroll
            for (int r = 0; r < 4; ++r)
                C[(size_t)(row0 + r) * D_OUT + col] = acc[mi][ni][r] + bv;
        }
    }
}

extern "C" void kernel_launch(void* const* d_in, const int* in_sizes, int n_in,
                              void* d_out, int out_size, void* d_ws, size_t ws_size,
                              hipStream_t stream) {
    (void)n_in; (void)out_size; (void)ws_size;
    const float* input    = (const float*)d_in[0];   // [2048,1024]
    const float* weight   = (const float*)d_in[1];   // [1024,8192]
    const float* bias     = (const float*)d_in[2];   // [8192]
    const int*   adj_rows = (const int*)d_in[3];     // [E]
    const int*   adj_cols = (const int*)d_in[4];     // [E]
    const float* adj_vals = (const float*)d_in[5];   // [E]
    const int E = in_sizes[3];

    // workspace layout (~37.6 MB; ws re-poisoned each call, everything below
    // is fully rewritten or explicitly zeroed every launch)
    char* ws = (char*)d_ws;
    unsigned short* wtb = (unsigned short*)ws;                                // 16 MB  W^T bf16
    unsigned short* wpt = (unsigned short*)(ws + (size_t)16 * 1024 * 1024);   // 16 MB  W'^T bf16
    unsigned short* abf = (unsigned short*)(ws + (size_t)32 * 1024 * 1024);   //  4 MB  X bf16
    int*   counts   = (int*)(ws + (size_t)36 * 1024 * 1024);                  // 32 KB
    int*   cursors  = counts + D_OUT;                                         // 32 KB
    int*   offsets  = cursors + D_OUT;                                        // 32 KB + 4
    int2*  csr_cv   = (int2*)(offsets + (D_OUT + 4));                         // 1 MB (8-B aligned)

    hipMemsetAsync(counts, 0, 2 * D_OUT * sizeof(int), stream);  // counts + cursors
    transpose_convert<<<dim3(D_OUT / 64, D_IN / 64), 256, 0, stream>>>(weight, wtb);
    convert_input<<<(N_ROWS * D_IN) / 1024, 256, 0, stream>>>(input, abf);
    count_rows<<<(E + 255) / 256, 256, 0, stream>>>(adj_rows, counts, E);
    scan_8192<<<1, 1024, 0, stream>>>(counts, offsets);
    fill_csr<<<(E + 255) / 256, 256, 0, stream>>>(adj_rows, adj_cols, adj_vals,
                                                  offsets, cursors, csr_cv, E);
    aggregate_rows<<<dim3(D_OUT / 2), 256, 0, stream>>>(
        wtb, offsets, csr_cv, wpt);
    gemm_bt_bias<<<dim3(D_OUT / 128, N_ROWS / 128), 256, 0, stream>>>(
        abf, wpt, bias, (float*)d_out);
}